// Round 1
// 660.301 us; speedup vs baseline: 1.0620x; 1.0620x over previous
//
#include <hip/hip_runtime.h>
#include <hip/hip_bf16.h>
#include <cmath>

#define HEADS 4
typedef __hip_bfloat16 bf16;
typedef short short8 __attribute__((ext_vector_type(8)));
typedef unsigned short us8 __attribute__((ext_vector_type(8)));
typedef float floatx4 __attribute__((ext_vector_type(4)));
typedef unsigned int u32;

__device__ inline float bf2f(unsigned short u) {
    union { unsigned u; float f; } c; c.u = ((unsigned)u) << 16; return c.f;
}
__device__ inline short f2bs(float f) {
    bf16 h = __float2bfloat16(f);
    return *reinterpret_cast<short*>(&h);
}

// async 16B global->LDS (DMA, no VGPR round-trip). LDS dest: wave-uniform base + lane*16.
__device__ __forceinline__ void ld_lds16(const void* g, void* l) {
    __builtin_amdgcn_global_load_lds((const __attribute__((address_space(1))) u32*)g,
                                     (__attribute__((address_space(3))) u32*)l, 16, 0, 0);
}

// ---- problem constants ----
__device__ const int g_ND[3]   = {50000, 10000, 2048};
__device__ const int g_COFF[3] = {0, 50000, 60000};
__device__ const int g_OOFF[3] = {0, 50001, 60002};
__device__ const int g_NB[3]   = {196, 40, 8};
__device__ const int g_NE[3]   = {800000, 400000, 100000};
__device__ const int g_SOFF[3] = {0, 800000, 1200000};
// coarse bucket width per layer: 128 buckets cover nd (128*S >= nd)
__device__ const int g_S[3]    = {391, 79, 16};

#define NBIN 128   // coarse dst-buckets per layer
#define NBLK 128   // edge-chunk blocks per layer for the partition pass
#define MAXB 8192  // max edges per bucket handled via LDS (avg 6250 for layer 0)

// ---------------- weights transpose-cast (5 slabs) + x cast, one dispatch ----------------
__global__ void precast_all(const float* __restrict__ W0, const float* __restrict__ W1,
                            const float* __restrict__ W2, const float* __restrict__ W3,
                            const float* __restrict__ W4, const float* __restrict__ x,
                            bf16* __restrict__ B0, bf16* __restrict__ B1, bf16* __restrict__ B2,
                            bf16* __restrict__ B3, bf16* __restrict__ B4, bf16* __restrict__ xb)
{
    int y = blockIdx.y;
    if (y == 5) {
        const float4* in = (const float4*)x;
        ushort4* out = (ushort4*)xb;
        const int n4 = 200000 * 128 / 4;
        for (int i = blockIdx.x * blockDim.x + threadIdx.x; i < n4; i += gridDim.x * blockDim.x) {
            float4 v = in[i];
            ushort4 o;
            o.x = (unsigned short)f2bs(v.x); o.y = (unsigned short)f2bs(v.y);
            o.z = (unsigned short)f2bs(v.z); o.w = (unsigned short)f2bs(v.w);
            out[i] = o;
        }
        return;
    }
    const int Ks[5] = {128, 256, 256, 128, 256};
    const int Ns[5] = {256, 256, 188, 256, 256};
    const float* W = (y == 0) ? W0 : (y == 1) ? W1 : (y == 2) ? W2 : (y == 3) ? W3 : W4;
    bf16* B = (y == 0) ? B0 : (y == 1) ? B1 : (y == 2) ? B2 : (y == 3) ? B3 : B4;
    int K = Ks[y], N = Ns[y], sz = K * N;
    for (int i = blockIdx.x * blockDim.x + threadIdx.x; i < sz; i += gridDim.x * blockDim.x) {
        int n = i / K, k = i % K;
        B[i] = __float2bfloat16(W[(size_t)k * N + n]);
    }
}

// ---------------- MFMA GEMM: C[M,N] = A[M,K] @ Bt[N,K]^T (all bf16 inputs) ----------------
template<int FUSE, int EL>
__global__ __launch_bounds__(256)
void gemm_mfma(const bf16* __restrict__ A, const bf16* __restrict__ Bt,
               const bf16* __restrict__ add, const float* __restrict__ bias,
               const float* __restrict__ al, const float* __restrict__ ar,
               float* __restrict__ el, float* __restrict__ er,
               bf16* __restrict__ Cb, int M, int N, int K, int nd)
{
    const int BM = 128, BN = 128, BK = 32;
    __shared__ short As[BM * BK];
    __shared__ short Bs[BN * BK];
    int tid = threadIdx.x;
    int wave = tid >> 6, lane = tid & 63;
    int q = lane >> 4, r = lane & 15;
    int row0 = blockIdx.y * BM, col0 = blockIdx.x * BN;
    int wm = (wave >> 1) * 64, wn = (wave & 1) * 64;

    const short* A16 = (const short*)A;
    const short* B16 = (const short*)Bt;
    const short* ga0 = A16 + (size_t)(row0 + (tid >> 2)) * K + (tid & 3) * 8;
    const short* ga1 = ga0 + (size_t)64 * K;
    const short* gb0 = B16 + (size_t)(col0 + (tid >> 2)) * K + (tid & 3) * 8;
    const short* gb1 = gb0 + (size_t)64 * K;
    char* la0 = (char*)As + tid * 16;
    char* la1 = la0 + 4096;
    char* lb0 = (char*)Bs + tid * 16;
    char* lb1 = lb0 + 4096;

    floatx4 zero = {0.f, 0.f, 0.f, 0.f};
    floatx4 acc[4][4];
#pragma unroll
    for (int i = 0; i < 4; i++)
#pragma unroll
        for (int j = 0; j < 4; j++) acc[i][j] = zero;

    for (int k0 = 0; k0 < K; k0 += BK) {
        ld_lds16(ga0, la0); ld_lds16(ga1, la1);
        ld_lds16(gb0, lb0); ld_lds16(gb1, lb1);
        ga0 += BK; ga1 += BK; gb0 += BK; gb1 += BK;
        __syncthreads();
        short8 af[4], bfr[4];
#pragma unroll
        for (int mt = 0; mt < 4; mt++) af[mt] = *(short8*)&As[(wm + mt * 16 + r) * BK + q * 8];
#pragma unroll
        for (int nt = 0; nt < 4; nt++) bfr[nt] = *(short8*)&Bs[(wn + nt * 16 + r) * BK + q * 8];
#pragma unroll
        for (int mt = 0; mt < 4; mt++)
#pragma unroll
            for (int nt = 0; nt < 4; nt++)
                acc[mt][nt] = __builtin_amdgcn_mfma_f32_16x16x32_bf16(af[mt], bfr[nt], acc[mt][nt], 0, 0, 0);
        __syncthreads();
    }

#pragma unroll
    for (int mt = 0; mt < 4; mt++) {
#pragma unroll
        for (int nt = 0; nt < 4; nt++) {
            int gcol = col0 + wn + nt * 16 + r;
            if (gcol >= N) continue;
#pragma unroll
            for (int e = 0; e < 4; e++) {
                int grow = row0 + wm + mt * 16 + q * 4 + e;
                if (grow >= M) continue;
                float v = acc[mt][nt][e];
                size_t idx = (size_t)grow * N + gcol;
                if (FUSE == 1) {
                    v += __bfloat162float(add[idx]) + bias[gcol];
                    v = (v > 0.f) ? v : (__expf(v) - 1.f);
                }
                Cb[idx] = __float2bfloat16(v);
            }
        }
    }

    if (EL) {
        int head = (col0 + wn) >> 6;
        float alh[4], arh[4];
#pragma unroll
        for (int nt = 0; nt < 4; nt++) {
            int c = nt * 16 + r;
            alh[nt] = al[head * 64 + c];
            arh[nt] = ar[head * 64 + c];
        }
#pragma unroll
        for (int mt = 0; mt < 4; mt++) {
#pragma unroll
            for (int e = 0; e < 4; e++) {
                float pl = 0.f, pr = 0.f;
#pragma unroll
                for (int nt = 0; nt < 4; nt++) {
                    float v = acc[mt][nt][e];
                    pl += v * alh[nt];
                    pr += v * arh[nt];
                }
#pragma unroll
                for (int off = 1; off < 16; off <<= 1) {
                    pl += __shfl_xor(pl, off);
                    pr += __shfl_xor(pr, off);
                }
                int grow = row0 + wm + mt * 16 + q * 4 + e;
                if (r == 0 && grow < M) {
                    el[grow * 4 + head] = pl;
                    if (grow < nd) er[grow * 4 + head] = pr;
                }
            }
        }
    }
}

// ---------------- el/er generic (layer 2, D=47) ----------------
__global__ void el_er_kernel(const bf16* __restrict__ fs, const float* __restrict__ al,
                             const float* __restrict__ ar, float* __restrict__ el,
                             float* __restrict__ er, int nd, int D)
{
    int n = blockIdx.x;
    int h = threadIdx.x >> 6;
    int d = threadIdx.x & 63;
    int HD = HEADS * D;
    float v = 0.f, a = 0.f, rr = 0.f;
    if (d < D) {
        v = __bfloat162float(fs[(size_t)n * HD + h * D + d]);
        a = al[h * D + d];
        rr = ar[h * D + d];
    }
    float pl = v * a, pr = v * rr;
    for (int off = 32; off; off >>= 1) {
        pl += __shfl_down(pl, off);
        pr += __shfl_down(pr, off);
    }
    if (d == 0) {
        el[n * HEADS + h] = pl;
        if (n < nd) er[n * HEADS + h] = pr;
    }
}

// ---------------- CSR build: per-dst histogram (for offs) ----------------
__global__ void hist3_kernel(const int* __restrict__ d0, const int* __restrict__ d1,
                             const int* __restrict__ d2, int* __restrict__ cnt)
{
    int i = blockIdx.x * blockDim.x + threadIdx.x;
    if (i >= 1300000) return;
    int base, d;
    if (i < 800000)       { base = 0;     d = d0[i]; }
    else if (i < 1200000) { base = 50000; d = d1[i - 800000]; }
    else                  { base = 60000; d = d2[i - 1200000]; }
    atomicAdd(&cnt[base + d], 1);
}

__global__ void scan_a3_kernel(const int* __restrict__ cnt, int* __restrict__ bsum)
{
    __shared__ int sdata[256];
    int l = blockIdx.y;
    if ((int)blockIdx.x >= g_NB[l]) return;
    int nd = g_ND[l], coff = g_COFF[l];
    int i = blockIdx.x * 256 + threadIdx.x;
    sdata[threadIdx.x] = (i < nd) ? cnt[coff + i] : 0;
    __syncthreads();
    for (int off = 128; off; off >>= 1) {
        if (threadIdx.x < off) sdata[threadIdx.x] += sdata[threadIdx.x + off];
        __syncthreads();
    }
    if (threadIdx.x == 0) bsum[l * 256 + blockIdx.x] = sdata[0];
}

__global__ void scan_b3_kernel(const int* __restrict__ bsum, int* __restrict__ bpre,
                               int* __restrict__ offs)
{
    __shared__ int sdata[256];
    int tid = threadIdx.x;
    for (int l = 0; l < 3; l++) {
        int v = (tid < g_NB[l]) ? bsum[l * 256 + tid] : 0;
        sdata[tid] = v;
        __syncthreads();
        for (int off = 1; off < 256; off <<= 1) {
            int t = (tid >= off) ? sdata[tid - off] : 0;
            __syncthreads();
            sdata[tid] += t;
            __syncthreads();
        }
        bpre[l * 256 + tid] = sdata[tid] - v;
        if (tid == 255) offs[g_OOFF[l] + g_ND[l]] = sdata[255];
        __syncthreads();
    }
}

__global__ void scan_c3_kernel(const int* __restrict__ cnt, const int* __restrict__ bpre,
                               int* __restrict__ offs)
{
    __shared__ int sdata[256];
    int l = blockIdx.y;
    if ((int)blockIdx.x >= g_NB[l]) return;
    int nd = g_ND[l], coff = g_COFF[l], ooff = g_OOFF[l];
    int tid = threadIdx.x;
    int i = blockIdx.x * 256 + tid;
    int v = (i < nd) ? cnt[coff + i] : 0;
    sdata[tid] = v;
    __syncthreads();
    for (int off = 1; off < 256; off <<= 1) {
        int t = (tid >= off) ? sdata[tid - off] : 0;
        __syncthreads();
        sdata[tid] += t;
        __syncthreads();
    }
    if (i < nd) {
        int e = bpre[l * 256 + blockIdx.x] + sdata[tid] - v;
        offs[ooff + i] = e;
    }
}

// ---------------- two-level radix partition by dst (replaces random scatter) ----------------
// Pass B1: per-(block, coarse-bucket) histogram. bucket = dst / S, NBIN buckets/layer.
__global__ __launch_bounds__(256)
void bin_hist(const int* __restrict__ d0, const int* __restrict__ d1,
              const int* __restrict__ d2, int* __restrict__ blockhist)
{
    int l = blockIdx.y;
    const int* dst = (l == 0) ? d0 : (l == 1) ? d1 : d2;
    int ne = g_NE[l], S = g_S[l];
    __shared__ int h[NBIN];
    for (int i = threadIdx.x; i < NBIN; i += blockDim.x) h[i] = 0;
    __syncthreads();
    int per = (ne + NBLK - 1) / NBLK;
    int st = blockIdx.x * per;
    int en = min(st + per, ne);
    for (int i = st + threadIdx.x; i < en; i += blockDim.x)
        atomicAdd(&h[dst[i] / S], 1);
    __syncthreads();
    for (int i = threadIdx.x; i < NBIN; i += blockDim.x)
        blockhist[(l * NBIN + i) * NBLK + blockIdx.x] = h[i];
}

// Pass B2: scan block-hists per bucket; anchor at offs[bucket*S] (CSR prefix already has it).
__global__ void bin_scan(const int* __restrict__ blockhist, const int* __restrict__ offs,
                         int* __restrict__ base)
{
    int l = blockIdx.y, bin = blockIdx.x;
    int S = g_S[l], nd = g_ND[l], ooff = g_OOFF[l];
    int t = threadIdx.x;
    __shared__ int s[NBLK];
    int v = blockhist[(l * NBIN + bin) * NBLK + t];
    s[t] = v;
    __syncthreads();
    for (int off = 1; off < NBLK; off <<= 1) {
        int tv = (t >= off) ? s[t - off] : 0;
        __syncthreads();
        s[t] += tv;
        __syncthreads();
    }
    int dlo = bin * S;
    if (dlo > nd) dlo = nd;
    int boffs = offs[ooff + dlo];
    base[(l * NBIN + bin) * NBLK + t] = boffs + s[t] - v;
}

// Pass B3: partition edges into coarse buckets. Same-(block,bucket) edges -> consecutive
// slots, written from one CU/XCD => L2 write-combines into full lines (vs 64B/edge before).
// Payload packed: src (<2^18) | local-dst (<512) << 18.
__global__ __launch_bounds__(256)
void bin_scatter(const int* __restrict__ s0, const int* __restrict__ d0,
                 const int* __restrict__ s1, const int* __restrict__ d1,
                 const int* __restrict__ s2, const int* __restrict__ d2,
                 const int* __restrict__ base, int* __restrict__ stage)
{
    int l = blockIdx.y;
    const int* src = (l == 0) ? s0 : (l == 1) ? s1 : s2;
    const int* dst = (l == 0) ? d0 : (l == 1) ? d1 : d2;
    int ne = g_NE[l], S = g_S[l], soff = g_SOFF[l];
    __shared__ int cur[NBIN];
    for (int i = threadIdx.x; i < NBIN; i += blockDim.x)
        cur[i] = base[(l * NBIN + i) * NBLK + blockIdx.x];
    __syncthreads();
    int per = (ne + NBLK - 1) / NBLK;
    int st = blockIdx.x * per;
    int en = min(st + per, ne);
    for (int i = st + threadIdx.x; i < en; i += blockDim.x) {
        int dv = dst[i];
        int b = dv / S;
        int ldst = dv - b * S;
        int p = atomicAdd(&cur[b], 1);
        stage[soff + p] = src[i] | (ldst << 18);
    }
}

// Pass B4: one block per bucket. Fine per-dst scatter entirely in LDS, then write the
// final ssrc segment fully coalesced.
__global__ __launch_bounds__(256)
void bin_expand(const int* __restrict__ stage, const int* __restrict__ offs,
                int* __restrict__ ssrc)
{
    int l = blockIdx.y, b = blockIdx.x;
    int S = g_S[l], nd = g_ND[l], ooff = g_OOFF[l], soff = g_SOFF[l];
    int dlo = b * S;
    if (dlo >= nd) return;
    int dhi = min(dlo + S, nd);
    int base = offs[ooff + dlo];
    int end  = offs[ooff + dhi];
    int cnt  = end - base;
    __shared__ int lcur[391];   // max S
    __shared__ int out[MAXB];
    for (int d = threadIdx.x; d < dhi - dlo; d += blockDim.x)
        lcur[d] = offs[ooff + dlo + d] - base;
    __syncthreads();
    if (cnt <= MAXB) {
        for (int i = threadIdx.x; i < cnt; i += blockDim.x) {
            int v = stage[soff + base + i];
            int sv = v & 0x3FFFF;
            int ld = v >> 18;
            int p = atomicAdd(&lcur[ld], 1);
            out[p] = sv;
        }
        __syncthreads();
        for (int i = threadIdx.x; i < cnt; i += blockDim.x)
            ssrc[soff + base + i] = out[i];
    } else {
        // safety fallback (never hit with these inputs): direct global scatter
        for (int i = threadIdx.x; i < cnt; i += blockDim.x) {
            int v = stage[soff + base + i];
            int sv = v & 0x3FFFF;
            int ld = v >> 18;
            int p = atomicAdd(&lcur[ld], 1);
            ssrc[soff + base + p] = sv;
        }
    }
}

// ---------------- fused attention+aggregation, D=64 (HD=256) ----------------
__global__ __launch_bounds__(256)
void attn_agg64(const bf16* __restrict__ fs, const float* __restrict__ el,
                const float* __restrict__ er, const float* __restrict__ b,
                const int* __restrict__ offs, const int* __restrict__ ssrc,
                bf16* __restrict__ rst, int nd)
{
    int wave = threadIdx.x >> 6, lane = threadIdx.x & 63;
    int n = blockIdx.x * 4 + wave;
    if (n >= nd) return;
    int s0 = offs[n], s1 = offs[n + 1];
    float4 erv = *(const float4*)&er[(size_t)n * 4];

    float m0 = -INFINITY, m1 = -INFINITY, m2 = -INFINITY, m3 = -INFINITY;
    for (int i = s0 + lane; i < s1; i += 64) {
        int sid = ssrc[i];
        float4 ev = *(const float4*)&el[(size_t)sid * 4];
        float e0 = ev.x + erv.x; e0 = (e0 > 0.f) ? e0 : 0.2f * e0;
        float e1 = ev.y + erv.y; e1 = (e1 > 0.f) ? e1 : 0.2f * e1;
        float e2 = ev.z + erv.z; e2 = (e2 > 0.f) ? e2 : 0.2f * e2;
        float e3 = ev.w + erv.w; e3 = (e3 > 0.f) ? e3 : 0.2f * e3;
        m0 = fmaxf(m0, e0); m1 = fmaxf(m1, e1); m2 = fmaxf(m2, e2); m3 = fmaxf(m3, e3);
    }
#pragma unroll
    for (int off = 32; off; off >>= 1) {
        m0 = fmaxf(m0, __shfl_xor(m0, off));
        m1 = fmaxf(m1, __shfl_xor(m1, off));
        m2 = fmaxf(m2, __shfl_xor(m2, off));
        m3 = fmaxf(m3, __shfl_xor(m3, off));
    }

    int half = lane >> 5, sub = lane & 31, head = sub >> 3;
    float mh  = (head == 0) ? m0 : (head == 1) ? m1 : (head == 2) ? m2 : m3;
    float eh  = (head == 0) ? erv.x : (head == 1) ? erv.y : (head == 2) ? erv.z : erv.w;
    const unsigned short* fsu = (const unsigned short*)fs;

    float acc[8];
#pragma unroll
    for (int j = 0; j < 8; j++) acc[j] = 0.f;
    float s = 0.f;

    int cnt = s1 - s0;
    int npairs = cnt >> 1;
    int i = s0 + half;
    if (npairs > 0) {
        int sid = ssrc[i];
        float ev = el[(size_t)sid * 4 + head];
        us8 f = *(const us8*)&fsu[(size_t)sid * 256 + sub * 8];
        for (int p = 1; p < npairs; p++) {
            i += 2;
            int sid2 = ssrc[i];
            float ev2 = el[(size_t)sid2 * 4 + head];
            us8 f2 = *(const us8*)&fsu[(size_t)sid2 * 256 + sub * 8];
            float e = ev + eh; e = (e > 0.f) ? e : 0.2f * e;
            float a = __expf(e - mh);
            s += a;
#pragma unroll
            for (int j = 0; j < 8; j++) acc[j] += a * bf2f(f[j]);
            ev = ev2; f = f2;
        }
        float e = ev + eh; e = (e > 0.f) ? e : 0.2f * e;
        float a = __expf(e - mh);
        s += a;
#pragma unroll
        for (int j = 0; j < 8; j++) acc[j] += a * bf2f(f[j]);
    }
    if (cnt & 1) {
        int idx = s1 - 1;
        int sid = ssrc[idx];
        float ev = el[(size_t)sid * 4 + head];
        us8 f = *(const us8*)&fsu[(size_t)sid * 256 + sub * 8];
        float e = ev + eh; e = (e > 0.f) ? e : 0.2f * e;
        float a = __expf(e - mh);
        if (half) a = 0.f;
        s += a;
#pragma unroll
        for (int j = 0; j < 8; j++) acc[j] += a * bf2f(f[j]);
    }
    s += __shfl_xor(s, 32);
#pragma unroll
    for (int j = 0; j < 8; j++) acc[j] += __shfl_xor(acc[j], 32);
    if (half == 0) {
        float inv = (s > 0.f) ? 1.f / s : 0.f;
        float4 b0 = *(const float4*)&b[sub * 8];
        float4 b1 = *(const float4*)&b[sub * 8 + 4];
        us8 o;
        o[0] = (unsigned short)f2bs(acc[0] * inv + b0.x);
        o[1] = (unsigned short)f2bs(acc[1] * inv + b0.y);
        o[2] = (unsigned short)f2bs(acc[2] * inv + b0.z);
        o[3] = (unsigned short)f2bs(acc[3] * inv + b0.w);
        o[4] = (unsigned short)f2bs(acc[4] * inv + b1.x);
        o[5] = (unsigned short)f2bs(acc[5] * inv + b1.y);
        o[6] = (unsigned short)f2bs(acc[6] * inv + b1.z);
        o[7] = (unsigned short)f2bs(acc[7] * inv + b1.w);
        *(us8*)&((unsigned short*)rst)[(size_t)n * 256 + sub * 8] = o;
    }
}

// ---------------- fused attention+aggregation generic (layer 2, D=47) ----------------
__global__ void attn_agg_gen(const bf16* __restrict__ fs, const float* __restrict__ el,
                             const float* __restrict__ er, const float* __restrict__ b,
                             const int* __restrict__ offs, const int* __restrict__ ssrc,
                             bf16* __restrict__ rst, int D, int nd)
{
    int wave = threadIdx.x >> 6, lane = threadIdx.x & 63;
    int n = blockIdx.x * 4 + wave;
    if (n >= nd) return;
    int HD = HEADS * D;
    int s0 = offs[n], s1 = offs[n + 1];
    float4 erv = *(const float4*)&er[(size_t)n * 4];

    float m0 = -INFINITY, m1 = -INFINITY, m2 = -INFINITY, m3 = -INFINITY;
    for (int i = s0 + lane; i < s1; i += 64) {
        int sid = ssrc[i];
        float4 ev = *(const float4*)&el[(size_t)sid * 4];
        float e0 = ev.x + erv.x; e0 = (e0 > 0.f) ? e0 : 0.2f * e0;
        float e1 = ev.y + erv.y; e1 = (e1 > 0.f) ? e1 : 0.2f * e1;
        float e2 = ev.z + erv.z; e2 = (e2 > 0.f) ? e2 : 0.2f * e2;
        float e3 = ev.w + erv.w; e3 = (e3 > 0.f) ? e3 : 0.2f * e3;
        m0 = fmaxf(m0, e0); m1 = fmaxf(m1, e1); m2 = fmaxf(m2, e2); m3 = fmaxf(m3, e3);
    }
#pragma unroll
    for (int off = 32; off; off >>= 1) {
        m0 = fmaxf(m0, __shfl_xor(m0, off));
        m1 = fmaxf(m1, __shfl_xor(m1, off));
        m2 = fmaxf(m2, __shfl_xor(m2, off));
        m3 = fmaxf(m3, __shfl_xor(m3, off));
    }

    bool act = (4 * lane) < HD;
    int h_[4];
#pragma unroll
    for (int j = 0; j < 4; j++) {
        int e = 4 * lane + j;
        h_[j] = (e < HD) ? (e / D) : 0;
    }
    float acc[4] = {0.f, 0.f, 0.f, 0.f};
    float sh[4] = {0.f, 0.f, 0.f, 0.f};
    const unsigned short* fsu = (const unsigned short*)fs;
    for (int i = s0; i < s1; i++) {
        int sid = ssrc[i];
        float4 ev = *(const float4*)&el[(size_t)sid * 4];
        float e0 = ev.x + erv.x; e0 = (e0 > 0.f) ? e0 : 0.2f * e0;
        float e1 = ev.y + erv.y; e1 = (e1 > 0.f) ? e1 : 0.2f * e1;
        float e2 = ev.z + erv.z; e2 = (e2 > 0.f) ? e2 : 0.2f * e2;
        float e3 = ev.w + erv.w; e3 = (e3 > 0.f) ? e3 : 0.2f * e3;
        float a4[4] = {__expf(e0 - m0), __expf(e1 - m1), __expf(e2 - m2), __expf(e3 - m3)};
        sh[0] += a4[0]; sh[1] += a4[1]; sh[2] += a4[2]; sh[3] += a4[3];
        ushort4 f = {0, 0, 0, 0};
        if (act) f = *(const ushort4*)&fsu[(size_t)sid * HD + 4 * lane];
        unsigned short fa[4] = {f.x, f.y, f.z, f.w};
#pragma unroll
        for (int j = 0; j < 4; j++)
            acc[j] += a4[h_[j]] * bf2f(fa[j]);
    }
    if (act) {
#pragma unroll
        for (int j = 0; j < 4; j++) {
            int e4 = 4 * lane + j;
            float sv = sh[h_[j]];
            float o = (sv > 0.f) ? acc[j] / sv : 0.f;
            rst[(size_t)n * HD + e4] = __float2bfloat16(o + b[e4]);
        }
    }
}

// ---------------- final layer ----------------
__global__ void final_kernel(const bf16* __restrict__ rst2, const bf16* __restrict__ h2,
                             const float* __restrict__ Ws, const float* __restrict__ bs,
                             float* __restrict__ out)
{
    const int K = 256, C = 47;
    int n = blockIdx.x;
    int c = threadIdx.x;
    float v = -INFINITY;
    if (c < C) {
        float dot = 0.f;
        for (int k = 0; k < K; k++) dot += __bfloat162float(h2[(size_t)n * K + k]) * Ws[k * C + c];
        float mean = 0.f;
#pragma unroll
        for (int hh = 0; hh < HEADS; hh++) mean += __bfloat162float(rst2[(size_t)n * HEADS * C + hh * C + c]);
        mean *= 0.25f;
        v = mean + dot + bs[c];
    }
    float mx = v;
    for (int off = 32; off; off >>= 1) mx = fmaxf(mx, __shfl_xor(mx, off));
    float ex = (c < C) ? __expf(v - mx) : 0.f;
    float sum = ex;
    for (int off = 32; off; off >>= 1) sum += __shfl_xor(sum, off);
    if (c < C) out[n * C + c] = v - mx - logf(sum);
}

extern "C" void kernel_launch(void* const* d_in, const int* in_sizes, int n_in,
                              void* d_out, int out_size, void* d_ws, size_t ws_size,
                              hipStream_t stream)
{
    const float* x = (const float*)d_in[0];
    const float* W[3]  = {(const float*)d_in[1],  (const float*)d_in[7],  (const float*)d_in[13]};
    const float* al[3] = {(const float*)d_in[2],  (const float*)d_in[8],  (const float*)d_in[14]};
    const float* ar[3] = {(const float*)d_in[3],  (const float*)d_in[9],  (const float*)d_in[15]};
    const float* bb[3] = {(const float*)d_in[4],  (const float*)d_in[10], (const float*)d_in[16]};
    const float* Ws[3] = {(const float*)d_in[5],  (const float*)d_in[11], (const float*)d_in[17]};
    const float* bs[3] = {(const float*)d_in[6],  (const float*)d_in[12], (const float*)d_in[18]};
    const int* srcp[3] = {(const int*)d_in[19], (const int*)d_in[21], (const int*)d_in[23]};
    const int* dstp[3] = {(const int*)d_in[20], (const int*)d_in[22], (const int*)d_in[24]};

    char* p = (char*)d_ws;
    auto alloc = [&](size_t bytes) -> void* {
        void* r = (void*)p;
        p += (bytes + 255) & ~(size_t)255;
        return r;
    };
    bf16*  xb    = (bf16*)alloc((size_t)200064 * 128 * 2);
    bf16*  fsb   = (bf16*)alloc((size_t)200000 * 256 * 2);
    bf16*  h1b   = (bf16*)alloc((size_t)50048 * 256 * 2);
    bf16*  h2b   = (bf16*)alloc((size_t)10112 * 256 * 2);
    bf16*  rstb  = (bf16*)alloc((size_t)50000 * 256 * 2);
    float* elb   = (float*)alloc((size_t)200000 * 4 * 4);
    float* erb   = (float*)alloc((size_t)50000 * 4 * 4);
    bf16* Wt[3]; bf16* Wst[2];
    Wt[0]  = (bf16*)alloc(256 * 128 * 2);
    Wt[1]  = (bf16*)alloc(256 * 256 * 2);
    Wt[2]  = (bf16*)alloc(256 * 256 * 2);
    Wst[0] = (bf16*)alloc(256 * 128 * 2);
    Wst[1] = (bf16*)alloc(256 * 256 * 2);
    int* counts    = (int*)alloc(62048 * 4);
    int* offs_all  = (int*)alloc(62051 * 4);
    int* ssrc_all  = (int*)alloc(1300000 * 4);
    int* stage_all = (int*)alloc(1300000 * 4);
    int* bsum      = (int*)alloc(768 * 4);
    int* bpre      = (int*)alloc(768 * 4);
    int* blockhist = (int*)alloc(3 * NBIN * NBLK * 4);
    int* binbase   = (int*)alloc(3 * NBIN * NBLK * 4);

    const int OOFF[3] = {0, 50001, 60002};
    const int SOFF[3] = {0, 800000, 1200000};
    const int EB = (1300000 + 255) / 256;   // one thread per edge

    precast_all<<<dim3(512, 6), 256, 0, stream>>>(W[0], W[1], W[2], Ws[0], Ws[1], x,
                                                  Wt[0], Wt[1], Wt[2], Wst[0], Wst[1], xb);

    hipMemsetAsync(counts, 0, 62048 * 4, stream);
    hist3_kernel<<<EB, 256, 0, stream>>>(dstp[0], dstp[1], dstp[2], counts);
    scan_a3_kernel<<<dim3(196, 3), 256, 0, stream>>>(counts, bsum);
    scan_b3_kernel<<<1, 256, 0, stream>>>(bsum, bpre, offs_all);
    scan_c3_kernel<<<dim3(196, 3), 256, 0, stream>>>(counts, bpre, offs_all);

    // two-level radix partition by dst -> ssrc_all (coalesced writes throughout)
    bin_hist<<<dim3(NBLK, 3), 256, 0, stream>>>(dstp[0], dstp[1], dstp[2], blockhist);
    bin_scan<<<dim3(NBIN, 3), NBLK, 0, stream>>>(blockhist, offs_all, binbase);
    bin_scatter<<<dim3(NBLK, 3), 256, 0, stream>>>(srcp[0], dstp[0], srcp[1], dstp[1],
                                                   srcp[2], dstp[2], binbase, stage_all);
    bin_expand<<<dim3(NBIN, 3), 256, 0, stream>>>(stage_all, offs_all, ssrc_all);

    // ---- layer 0 (D=64, cin=128) ----
    gemm_mfma<0, 1><<<dim3(2, 1563), 256, 0, stream>>>(
        xb, Wt[0], nullptr, nullptr, al[0], ar[0], elb, erb, fsb, 200000, 256, 128, 50000);
    attn_agg64<<<12500, 256, 0, stream>>>(fsb, elb, erb, bb[0], offs_all + OOFF[0], ssrc_all + SOFF[0], rstb, 50000);
    gemm_mfma<1, 0><<<dim3(2, 391), 256, 0, stream>>>(
        xb, Wst[0], rstb, bs[0], nullptr, nullptr, nullptr, nullptr, h1b, 50000, 256, 128, 0);

    // ---- layer 1 (D=64, cin=256) ----
    gemm_mfma<0, 1><<<dim3(2, 391), 256, 0, stream>>>(
        h1b, Wt[1], nullptr, nullptr, al[1], ar[1], elb, erb, fsb, 50000, 256, 256, 10000);
    attn_agg64<<<2500, 256, 0, stream>>>(fsb, elb, erb, bb[1], offs_all + OOFF[1], ssrc_all + SOFF[1], rstb, 10000);
    gemm_mfma<1, 0><<<dim3(2, 79), 256, 0, stream>>>(
        h1b, Wst[1], rstb, bs[1], nullptr, nullptr, nullptr, nullptr, h2b, 10000, 256, 256, 0);

    // ---- layer 2 (D=47, cin=256) ----
    gemm_mfma<0, 0><<<dim3(2, 79), 256, 0, stream>>>(
        h2b, Wt[2], nullptr, nullptr, nullptr, nullptr, nullptr, nullptr, fsb, 10000, 188, 256, 0);
    el_er_kernel<<<10000, 256, 0, stream>>>(fsb, al[2], ar[2], elb, erb, 2048, 47);
    attn_agg_gen<<<512, 256, 0, stream>>>(fsb, elb, erb, bb[2], offs_all + OOFF[2], ssrc_all + SOFF[2], rstb, 47, 2048);
    final_kernel<<<2048, 64, 0, stream>>>(rstb, h2b, Ws[2], bs[2], (float*)d_out);
}

// Round 2
// 592.633 us; speedup vs baseline: 1.1832x; 1.1142x over previous
//
#include <hip/hip_runtime.h>
#include <hip/hip_bf16.h>
#include <cmath>

#define HEADS 4
typedef __hip_bfloat16 bf16;
typedef short short8 __attribute__((ext_vector_type(8)));
typedef unsigned short us8 __attribute__((ext_vector_type(8)));
typedef float floatx4 __attribute__((ext_vector_type(4)));
typedef unsigned int u32;

__device__ inline float bf2f(unsigned short u) {
    union { unsigned u; float f; } c; c.u = ((unsigned)u) << 16; return c.f;
}
__device__ inline short f2bs(float f) {
    bf16 h = __float2bfloat16(f);
    return *reinterpret_cast<short*>(&h);
}

// async 16B global->LDS (DMA, no VGPR round-trip). LDS dest: wave-uniform base + lane*16.
__device__ __forceinline__ void ld_lds16(const void* g, void* l) {
    __builtin_amdgcn_global_load_lds((const __attribute__((address_space(1))) u32*)g,
                                     (__attribute__((address_space(3))) u32*)l, 16, 0, 0);
}

// ---- problem constants ----
__device__ const int g_ND[3]   = {50000, 10000, 2048};
__device__ const int g_OOFF[3] = {0, 50001, 60002};
__device__ const int g_NE[3]   = {800000, 400000, 100000};
__device__ const int g_SOFF[3] = {0, 800000, 1200000};
// coarse bucket width per layer: 128 buckets cover nd (128*S >= nd)
__device__ const int g_S[3]    = {391, 79, 16};

#define NBIN 128   // coarse dst-buckets per layer
#define NBLK 128   // edge-chunk blocks per layer for the partition pass
#define MAXB 8192  // max edges per bucket handled via LDS (avg 6250 for layer 0)
#define MAXS 391   // max fine dsts per bucket

// ---------------- weights transpose-cast (5 slabs) + x cast, one dispatch ----------------
__global__ void precast_all(const float* __restrict__ W0, const float* __restrict__ W1,
                            const float* __restrict__ W2, const float* __restrict__ W3,
                            const float* __restrict__ W4, const float* __restrict__ x,
                            bf16* __restrict__ B0, bf16* __restrict__ B1, bf16* __restrict__ B2,
                            bf16* __restrict__ B3, bf16* __restrict__ B4, bf16* __restrict__ xb)
{
    int y = blockIdx.y;
    if (y == 5) {
        const float4* in = (const float4*)x;
        ushort4* out = (ushort4*)xb;
        const int n4 = 200000 * 128 / 4;
        for (int i = blockIdx.x * blockDim.x + threadIdx.x; i < n4; i += gridDim.x * blockDim.x) {
            float4 v = in[i];
            ushort4 o;
            o.x = (unsigned short)f2bs(v.x); o.y = (unsigned short)f2bs(v.y);
            o.z = (unsigned short)f2bs(v.z); o.w = (unsigned short)f2bs(v.w);
            out[i] = o;
        }
        return;
    }
    const int Ks[5] = {128, 256, 256, 128, 256};
    const int Ns[5] = {256, 256, 188, 256, 256};
    const float* W = (y == 0) ? W0 : (y == 1) ? W1 : (y == 2) ? W2 : (y == 3) ? W3 : W4;
    bf16* B = (y == 0) ? B0 : (y == 1) ? B1 : (y == 2) ? B2 : (y == 3) ? B3 : B4;
    int K = Ks[y], N = Ns[y], sz = K * N;
    for (int i = blockIdx.x * blockDim.x + threadIdx.x; i < sz; i += gridDim.x * blockDim.x) {
        int n = i / K, k = i % K;
        B[i] = __float2bfloat16(W[(size_t)k * N + n]);
    }
}

// ---------------- MFMA GEMM: C[M,N] = A[M,K] @ Bt[N,K]^T (all bf16 inputs) ----------------
template<int FUSE, int EL>
__global__ __launch_bounds__(256)
void gemm_mfma(const bf16* __restrict__ A, const bf16* __restrict__ Bt,
               const bf16* __restrict__ add, const float* __restrict__ bias,
               const float* __restrict__ al, const float* __restrict__ ar,
               float* __restrict__ el, float* __restrict__ er,
               bf16* __restrict__ Cb, int M, int N, int K, int nd)
{
    const int BM = 128, BN = 128, BK = 32;
    __shared__ short As[BM * BK];
    __shared__ short Bs[BN * BK];
    int tid = threadIdx.x;
    int wave = tid >> 6, lane = tid & 63;
    int q = lane >> 4, r = lane & 15;
    int row0 = blockIdx.y * BM, col0 = blockIdx.x * BN;
    int wm = (wave >> 1) * 64, wn = (wave & 1) * 64;

    const short* A16 = (const short*)A;
    const short* B16 = (const short*)Bt;
    const short* ga0 = A16 + (size_t)(row0 + (tid >> 2)) * K + (tid & 3) * 8;
    const short* ga1 = ga0 + (size_t)64 * K;
    const short* gb0 = B16 + (size_t)(col0 + (tid >> 2)) * K + (tid & 3) * 8;
    const short* gb1 = gb0 + (size_t)64 * K;
    char* la0 = (char*)As + tid * 16;
    char* la1 = la0 + 4096;
    char* lb0 = (char*)Bs + tid * 16;
    char* lb1 = lb0 + 4096;

    floatx4 zero = {0.f, 0.f, 0.f, 0.f};
    floatx4 acc[4][4];
#pragma unroll
    for (int i = 0; i < 4; i++)
#pragma unroll
        for (int j = 0; j < 4; j++) acc[i][j] = zero;

    for (int k0 = 0; k0 < K; k0 += BK) {
        ld_lds16(ga0, la0); ld_lds16(ga1, la1);
        ld_lds16(gb0, lb0); ld_lds16(gb1, lb1);
        ga0 += BK; ga1 += BK; gb0 += BK; gb1 += BK;
        __syncthreads();
        short8 af[4], bfr[4];
#pragma unroll
        for (int mt = 0; mt < 4; mt++) af[mt] = *(short8*)&As[(wm + mt * 16 + r) * BK + q * 8];
#pragma unroll
        for (int nt = 0; nt < 4; nt++) bfr[nt] = *(short8*)&Bs[(wn + nt * 16 + r) * BK + q * 8];
#pragma unroll
        for (int mt = 0; mt < 4; mt++)
#pragma unroll
            for (int nt = 0; nt < 4; nt++)
                acc[mt][nt] = __builtin_amdgcn_mfma_f32_16x16x32_bf16(af[mt], bfr[nt], acc[mt][nt], 0, 0, 0);
        __syncthreads();
    }

#pragma unroll
    for (int mt = 0; mt < 4; mt++) {
#pragma unroll
        for (int nt = 0; nt < 4; nt++) {
            int gcol = col0 + wn + nt * 16 + r;
            if (gcol >= N) continue;
#pragma unroll
            for (int e = 0; e < 4; e++) {
                int grow = row0 + wm + mt * 16 + q * 4 + e;
                if (grow >= M) continue;
                float v = acc[mt][nt][e];
                size_t idx = (size_t)grow * N + gcol;
                if (FUSE == 1) {
                    v += __bfloat162float(add[idx]) + bias[gcol];
                    v = (v > 0.f) ? v : (__expf(v) - 1.f);
                }
                Cb[idx] = __float2bfloat16(v);
            }
        }
    }

    if (EL) {
        int head = (col0 + wn) >> 6;
        float alh[4], arh[4];
#pragma unroll
        for (int nt = 0; nt < 4; nt++) {
            int c = nt * 16 + r;
            alh[nt] = al[head * 64 + c];
            arh[nt] = ar[head * 64 + c];
        }
#pragma unroll
        for (int mt = 0; mt < 4; mt++) {
#pragma unroll
            for (int e = 0; e < 4; e++) {
                float pl = 0.f, pr = 0.f;
#pragma unroll
                for (int nt = 0; nt < 4; nt++) {
                    float v = acc[mt][nt][e];
                    pl += v * alh[nt];
                    pr += v * arh[nt];
                }
#pragma unroll
                for (int off = 1; off < 16; off <<= 1) {
                    pl += __shfl_xor(pl, off);
                    pr += __shfl_xor(pr, off);
                }
                int grow = row0 + wm + mt * 16 + q * 4 + e;
                if (r == 0 && grow < M) {
                    el[grow * 4 + head] = pl;
                    if (grow < nd) er[grow * 4 + head] = pr;
                }
            }
        }
    }
}

// ---------------- el/er generic (layer 2, D=47) ----------------
__global__ void el_er_kernel(const bf16* __restrict__ fs, const float* __restrict__ al,
                             const float* __restrict__ ar, float* __restrict__ el,
                             float* __restrict__ er, int nd, int D)
{
    int n = blockIdx.x;
    int h = threadIdx.x >> 6;
    int d = threadIdx.x & 63;
    int HD = HEADS * D;
    float v = 0.f, a = 0.f, rr = 0.f;
    if (d < D) {
        v = __bfloat162float(fs[(size_t)n * HD + h * D + d]);
        a = al[h * D + d];
        rr = ar[h * D + d];
    }
    float pl = v * a, pr = v * rr;
    for (int off = 32; off; off >>= 1) {
        pl += __shfl_down(pl, off);
        pr += __shfl_down(pr, off);
    }
    if (d == 0) {
        el[n * HEADS + h] = pl;
        if (n < nd) er[n * HEADS + h] = pr;
    }
}

// ---------------- two-level radix partition by dst (also builds CSR offs) ----------------
// Pass B1: per-(block, coarse-bucket) histogram. bucket = dst / S, NBIN buckets/layer.
__global__ __launch_bounds__(256)
void bin_hist(const int* __restrict__ d0, const int* __restrict__ d1,
              const int* __restrict__ d2, int* __restrict__ blockhist)
{
    int l = blockIdx.y;
    const int* dst = (l == 0) ? d0 : (l == 1) ? d1 : d2;
    int ne = g_NE[l], S = g_S[l];
    __shared__ int h[NBIN];
    for (int i = threadIdx.x; i < NBIN; i += blockDim.x) h[i] = 0;
    __syncthreads();
    int per = (ne + NBLK - 1) / NBLK;
    int st = blockIdx.x * per;
    int en = min(st + per, ne);
    for (int i = st + threadIdx.x; i < en; i += blockDim.x)
        atomicAdd(&h[dst[i] / S], 1);
    __syncthreads();
    for (int i = threadIdx.x; i < NBIN; i += blockDim.x)
        blockhist[(l * NBIN + i) * NBLK + blockIdx.x] = h[i];
}

// Pass B2a: bucket totals -> exclusive scan -> bucket bases. One block per layer, 128 thr.
__global__ void coarse_scan(const int* __restrict__ blockhist, int* __restrict__ bbase,
                            int* __restrict__ offs)
{
    int l = blockIdx.x;
    int t = threadIdx.x;   // 0..127
    __shared__ int s[NBIN];
    int tot = 0;
    for (int k = 0; k < NBLK; k++) tot += blockhist[(l * NBIN + t) * NBLK + k];
    s[t] = tot;
    __syncthreads();
    for (int off = 1; off < NBIN; off <<= 1) {
        int a = (t >= off) ? s[t - off] : 0;
        __syncthreads();
        s[t] += a;
        __syncthreads();
    }
    bbase[l * (NBIN + 1) + t + 1] = s[t];
    if (t == 0) {
        bbase[l * (NBIN + 1)] = 0;
        offs[g_OOFF[l] + g_ND[l]] = g_NE[l];
    }
}

// Pass B2b: per-bucket scan across blocks, anchored at bucket base.
__global__ void bin_scan(const int* __restrict__ blockhist, const int* __restrict__ bbase,
                         int* __restrict__ base)
{
    int l = blockIdx.y, bin = blockIdx.x;
    int t = threadIdx.x;  // 0..NBLK-1
    __shared__ int s[NBLK];
    int v = blockhist[(l * NBIN + bin) * NBLK + t];
    s[t] = v;
    __syncthreads();
    for (int off = 1; off < NBLK; off <<= 1) {
        int a = (t >= off) ? s[t - off] : 0;
        __syncthreads();
        s[t] += a;
        __syncthreads();
    }
    base[(l * NBIN + bin) * NBLK + t] = bbase[l * (NBIN + 1) + bin] + s[t] - v;
}

// Pass B3: partition edges into coarse buckets. Same-(block,bucket) edges -> consecutive
// slots => L2 write-combines into full lines. Payload: src | local-dst << 18.
__global__ __launch_bounds__(256)
void bin_scatter(const int* __restrict__ s0, const int* __restrict__ d0,
                 const int* __restrict__ s1, const int* __restrict__ d1,
                 const int* __restrict__ s2, const int* __restrict__ d2,
                 const int* __restrict__ base, int* __restrict__ stage)
{
    int l = blockIdx.y;
    const int* src = (l == 0) ? s0 : (l == 1) ? s1 : s2;
    const int* dst = (l == 0) ? d0 : (l == 1) ? d1 : d2;
    int ne = g_NE[l], S = g_S[l], soff = g_SOFF[l];
    __shared__ int cur[NBIN];
    for (int i = threadIdx.x; i < NBIN; i += blockDim.x)
        cur[i] = base[(l * NBIN + i) * NBLK + blockIdx.x];
    __syncthreads();
    int per = (ne + NBLK - 1) / NBLK;
    int st = blockIdx.x * per;
    int en = min(st + per, ne);
    for (int i = st + threadIdx.x; i < en; i += blockDim.x) {
        int dv = dst[i];
        int b = dv / S;
        int ldst = dv - b * S;
        int p = atomicAdd(&cur[b], 1);
        stage[soff + p] = src[i] | (ldst << 18);
    }
}

// Pass B4: one block per bucket. Fine histogram + scan (-> offs, coalesced) and fine
// per-dst scatter, all in LDS; final ssrc segment written fully coalesced.
__global__ __launch_bounds__(256)
void bin_expand(const int* __restrict__ stage, const int* __restrict__ bbase,
                int* __restrict__ offs, int* __restrict__ ssrc)
{
    int l = blockIdx.y, b = blockIdx.x;
    int S = g_S[l], nd = g_ND[l], ooff = g_OOFF[l], soff = g_SOFF[l];
    int dlo = b * S;
    if (dlo >= nd) return;
    int dhi = min(dlo + S, nd);
    int base = bbase[l * (NBIN + 1) + b];
    int end  = bbase[l * (NBIN + 1) + b + 1];
    int cnt  = end - base;
    int tid = threadIdx.x;
    __shared__ int sdata[MAXB];
    __shared__ int outb[MAXB];
    __shared__ int lh[512];
    __shared__ int lcur[MAXS];
    lh[tid] = 0; lh[tid + 256] = 0;
    __syncthreads();
    if (cnt <= MAXB) {
        for (int i = tid; i < cnt; i += 256) {
            int v = stage[soff + base + i];
            sdata[i] = v;
            atomicAdd(&lh[v >> 18], 1);
        }
        __syncthreads();
        // inclusive scan over 512 (2 elems/thread, read-all-then-write-all)
        for (int off = 1; off < 512; off <<= 1) {
            int a0 = (tid >= off) ? lh[tid - off] : 0;
            int a1 = lh[tid + 256 - off];
            __syncthreads();
            lh[tid] += a0; lh[tid + 256] += a1;
            __syncthreads();
        }
        for (int d = tid; d < dhi - dlo; d += 256) {
            int ex = (d == 0) ? 0 : lh[d - 1];
            offs[ooff + dlo + d] = base + ex;
            lcur[d] = ex;
        }
        __syncthreads();
        for (int i = tid; i < cnt; i += 256) {
            int v = sdata[i];
            int p = atomicAdd(&lcur[v >> 18], 1);
            outb[p] = v & 0x3FFFF;
        }
        __syncthreads();
        for (int i = tid; i < cnt; i += 256)
            ssrc[soff + base + i] = outb[i];
    } else {
        // safety fallback (never hit with these inputs)
        for (int i = tid; i < cnt; i += 256)
            atomicAdd(&lh[stage[soff + base + i] >> 18], 1);
        __syncthreads();
        for (int off = 1; off < 512; off <<= 1) {
            int a0 = (tid >= off) ? lh[tid - off] : 0;
            int a1 = lh[tid + 256 - off];
            __syncthreads();
            lh[tid] += a0; lh[tid + 256] += a1;
            __syncthreads();
        }
        for (int d = tid; d < dhi - dlo; d += 256) {
            int ex = (d == 0) ? 0 : lh[d - 1];
            offs[ooff + dlo + d] = base + ex;
            lcur[d] = ex;
        }
        __syncthreads();
        for (int i = tid; i < cnt; i += 256) {
            int v = stage[soff + base + i];
            int p = atomicAdd(&lcur[v >> 18], 1);
            ssrc[soff + base + p] = v & 0x3FFFF;
        }
    }
}

// ---------------- fused attention+aggregation, D=64 (HD=256), no-max softmax ----------------
__global__ __launch_bounds__(256)
void attn_agg64(const bf16* __restrict__ fs, const float* __restrict__ el,
                const float* __restrict__ er, const float* __restrict__ b,
                const int* __restrict__ offs, const int* __restrict__ ssrc,
                bf16* __restrict__ rst, int nd)
{
    int wave = threadIdx.x >> 6, lane = threadIdx.x & 63;
    int n = blockIdx.x * 4 + wave;
    if (n >= nd) return;
    int s0 = offs[n], s1 = offs[n + 1];
    float4 erv = *(const float4*)&er[(size_t)n * 4];

    int half = lane >> 5, sub = lane & 31, head = sub >> 3;
    float eh  = (head == 0) ? erv.x : (head == 1) ? erv.y : (head == 2) ? erv.z : erv.w;
    const unsigned short* fsu = (const unsigned short*)fs;

    float acc[8];
#pragma unroll
    for (int j = 0; j < 8; j++) acc[j] = 0.f;
    float s = 0.f;

    int cnt = s1 - s0;
    int npairs = cnt >> 1;
    int i = s0 + half;
    if (npairs > 0) {
        int sid = ssrc[i];
        float ev = el[(size_t)sid * 4 + head];
        us8 f = *(const us8*)&fsu[(size_t)sid * 256 + sub * 8];
        for (int p = 1; p < npairs; p++) {
            i += 2;
            int sid2 = ssrc[i];
            float ev2 = el[(size_t)sid2 * 4 + head];
            us8 f2 = *(const us8*)&fsu[(size_t)sid2 * 256 + sub * 8];
            float e = ev + eh; e = (e > 0.f) ? e : 0.2f * e;
            float a = __expf(fminf(e, 60.f));
            s += a;
#pragma unroll
            for (int j = 0; j < 8; j++) acc[j] += a * bf2f(f[j]);
            ev = ev2; f = f2;
        }
        float e = ev + eh; e = (e > 0.f) ? e : 0.2f * e;
        float a = __expf(fminf(e, 60.f));
        s += a;
#pragma unroll
        for (int j = 0; j < 8; j++) acc[j] += a * bf2f(f[j]);
    }
    if (cnt & 1) {
        int idx = s1 - 1;
        int sid = ssrc[idx];
        float ev = el[(size_t)sid * 4 + head];
        us8 f = *(const us8*)&fsu[(size_t)sid * 256 + sub * 8];
        float e = ev + eh; e = (e > 0.f) ? e : 0.2f * e;
        float a = __expf(fminf(e, 60.f));
        if (half) a = 0.f;
        s += a;
#pragma unroll
        for (int j = 0; j < 8; j++) acc[j] += a * bf2f(f[j]);
    }
    s += __shfl_xor(s, 32);
#pragma unroll
    for (int j = 0; j < 8; j++) acc[j] += __shfl_xor(acc[j], 32);
    if (half == 0) {
        float inv = (s > 0.f) ? 1.f / s : 0.f;
        float4 b0 = *(const float4*)&b[sub * 8];
        float4 b1 = *(const float4*)&b[sub * 8 + 4];
        us8 o;
        o[0] = (unsigned short)f2bs(acc[0] * inv + b0.x);
        o[1] = (unsigned short)f2bs(acc[1] * inv + b0.y);
        o[2] = (unsigned short)f2bs(acc[2] * inv + b0.z);
        o[3] = (unsigned short)f2bs(acc[3] * inv + b0.w);
        o[4] = (unsigned short)f2bs(acc[4] * inv + b1.x);
        o[5] = (unsigned short)f2bs(acc[5] * inv + b1.y);
        o[6] = (unsigned short)f2bs(acc[6] * inv + b1.z);
        o[7] = (unsigned short)f2bs(acc[7] * inv + b1.w);
        *(us8*)&((unsigned short*)rst)[(size_t)n * 256 + sub * 8] = o;
    }
}

// ---------------- fused attention+aggregation generic (layer 2, D=47), no-max ----------------
__global__ void attn_agg_gen(const bf16* __restrict__ fs, const float* __restrict__ el,
                             const float* __restrict__ er, const float* __restrict__ b,
                             const int* __restrict__ offs, const int* __restrict__ ssrc,
                             bf16* __restrict__ rst, int D, int nd)
{
    int wave = threadIdx.x >> 6, lane = threadIdx.x & 63;
    int n = blockIdx.x * 4 + wave;
    if (n >= nd) return;
    int HD = HEADS * D;
    int s0 = offs[n], s1 = offs[n + 1];
    float4 erv = *(const float4*)&er[(size_t)n * 4];

    bool act = (4 * lane) < HD;
    int h_[4];
#pragma unroll
    for (int j = 0; j < 4; j++) {
        int e = 4 * lane + j;
        h_[j] = (e < HD) ? (e / D) : 0;
    }
    float acc[4] = {0.f, 0.f, 0.f, 0.f};
    float sh[4] = {0.f, 0.f, 0.f, 0.f};
    const unsigned short* fsu = (const unsigned short*)fs;
    for (int i = s0; i < s1; i++) {
        int sid = ssrc[i];
        float4 ev = *(const float4*)&el[(size_t)sid * 4];
        float e0 = ev.x + erv.x; e0 = (e0 > 0.f) ? e0 : 0.2f * e0;
        float e1 = ev.y + erv.y; e1 = (e1 > 0.f) ? e1 : 0.2f * e1;
        float e2 = ev.z + erv.z; e2 = (e2 > 0.f) ? e2 : 0.2f * e2;
        float e3 = ev.w + erv.w; e3 = (e3 > 0.f) ? e3 : 0.2f * e3;
        float a4[4] = {__expf(fminf(e0, 60.f)), __expf(fminf(e1, 60.f)),
                       __expf(fminf(e2, 60.f)), __expf(fminf(e3, 60.f))};
        sh[0] += a4[0]; sh[1] += a4[1]; sh[2] += a4[2]; sh[3] += a4[3];
        ushort4 f = {0, 0, 0, 0};
        if (act) f = *(const ushort4*)&fsu[(size_t)sid * HD + 4 * lane];
        unsigned short fa[4] = {f.x, f.y, f.z, f.w};
#pragma unroll
        for (int j = 0; j < 4; j++)
            acc[j] += a4[h_[j]] * bf2f(fa[j]);
    }
    if (act) {
#pragma unroll
        for (int j = 0; j < 4; j++) {
            int e4 = 4 * lane + j;
            float sv = sh[h_[j]];
            float o = (sv > 0.f) ? acc[j] / sv : 0.f;
            rst[(size_t)n * HD + e4] = __float2bfloat16(o + b[e4]);
        }
    }
}

// ---------------- final layer ----------------
__global__ void final_kernel(const bf16* __restrict__ rst2, const bf16* __restrict__ h2,
                             const float* __restrict__ Ws, const float* __restrict__ bs,
                             float* __restrict__ out)
{
    const int K = 256, C = 47;
    int n = blockIdx.x;
    int c = threadIdx.x;
    float v = -INFINITY;
    if (c < C) {
        float dot = 0.f;
        for (int k = 0; k < K; k++) dot += __bfloat162float(h2[(size_t)n * K + k]) * Ws[k * C + c];
        float mean = 0.f;
#pragma unroll
        for (int hh = 0; hh < HEADS; hh++) mean += __bfloat162float(rst2[(size_t)n * HEADS * C + hh * C + c]);
        mean *= 0.25f;
        v = mean + dot + bs[c];
    }
    float mx = v;
    for (int off = 32; off; off >>= 1) mx = fmaxf(mx, __shfl_xor(mx, off));
    float ex = (c < C) ? __expf(v - mx) : 0.f;
    float sum = ex;
    for (int off = 32; off; off >>= 1) sum += __shfl_xor(sum, off);
    if (c < C) out[n * C + c] = v - mx - logf(sum);
}

extern "C" void kernel_launch(void* const* d_in, const int* in_sizes, int n_in,
                              void* d_out, int out_size, void* d_ws, size_t ws_size,
                              hipStream_t stream)
{
    const float* x = (const float*)d_in[0];
    const float* W[3]  = {(const float*)d_in[1],  (const float*)d_in[7],  (const float*)d_in[13]};
    const float* al[3] = {(const float*)d_in[2],  (const float*)d_in[8],  (const float*)d_in[14]};
    const float* ar[3] = {(const float*)d_in[3],  (const float*)d_in[9],  (const float*)d_in[15]};
    const float* bb[3] = {(const float*)d_in[4],  (const float*)d_in[10], (const float*)d_in[16]};
    const float* Ws[3] = {(const float*)d_in[5],  (const float*)d_in[11], (const float*)d_in[17]};
    const float* bs[3] = {(const float*)d_in[6],  (const float*)d_in[12], (const float*)d_in[18]};
    const int* srcp[3] = {(const int*)d_in[19], (const int*)d_in[21], (const int*)d_in[23]};
    const int* dstp[3] = {(const int*)d_in[20], (const int*)d_in[22], (const int*)d_in[24]};

    char* p = (char*)d_ws;
    auto alloc = [&](size_t bytes) -> void* {
        void* r = (void*)p;
        p += (bytes + 255) & ~(size_t)255;
        return r;
    };
    bf16*  xb    = (bf16*)alloc((size_t)200064 * 128 * 2);
    bf16*  fsb   = (bf16*)alloc((size_t)200000 * 256 * 2);
    bf16*  h1b   = (bf16*)alloc((size_t)50048 * 256 * 2);
    bf16*  h2b   = (bf16*)alloc((size_t)10112 * 256 * 2);
    bf16*  rstb  = (bf16*)alloc((size_t)50000 * 256 * 2);
    float* elb   = (float*)alloc((size_t)200000 * 4 * 4);
    float* erb   = (float*)alloc((size_t)50000 * 4 * 4);
    bf16* Wt[3]; bf16* Wst[2];
    Wt[0]  = (bf16*)alloc(256 * 128 * 2);
    Wt[1]  = (bf16*)alloc(256 * 256 * 2);
    Wt[2]  = (bf16*)alloc(256 * 256 * 2);
    Wst[0] = (bf16*)alloc(256 * 128 * 2);
    Wst[1] = (bf16*)alloc(256 * 256 * 2);
    int* offs_all  = (int*)alloc(62051 * 4);
    int* ssrc_all  = (int*)alloc(1300000 * 4);
    int* stage_all = (int*)alloc(1300000 * 4);
    int* blockhist = (int*)alloc(3 * NBIN * NBLK * 4);
    int* binbase   = (int*)alloc(3 * NBIN * NBLK * 4);
    int* bbase     = (int*)alloc(3 * (NBIN + 1) * 4);

    const int OOFF[3] = {0, 50001, 60002};
    const int SOFF[3] = {0, 800000, 1200000};

    precast_all<<<dim3(512, 6), 256, 0, stream>>>(W[0], W[1], W[2], Ws[0], Ws[1], x,
                                                  Wt[0], Wt[1], Wt[2], Wst[0], Wst[1], xb);

    // two-level radix partition by dst -> ssrc_all + CSR offs (coalesced writes throughout)
    bin_hist<<<dim3(NBLK, 3), 256, 0, stream>>>(dstp[0], dstp[1], dstp[2], blockhist);
    coarse_scan<<<3, NBIN, 0, stream>>>(blockhist, bbase, offs_all);
    bin_scan<<<dim3(NBIN, 3), NBLK, 0, stream>>>(blockhist, bbase, binbase);
    bin_scatter<<<dim3(NBLK, 3), 256, 0, stream>>>(srcp[0], dstp[0], srcp[1], dstp[1],
                                                   srcp[2], dstp[2], binbase, stage_all);
    bin_expand<<<dim3(NBIN, 3), 256, 0, stream>>>(stage_all, bbase, offs_all, ssrc_all);

    // ---- layer 0 (D=64, cin=128) ----
    gemm_mfma<0, 1><<<dim3(2, 1563), 256, 0, stream>>>(
        xb, Wt[0], nullptr, nullptr, al[0], ar[0], elb, erb, fsb, 200000, 256, 128, 50000);
    attn_agg64<<<12500, 256, 0, stream>>>(fsb, elb, erb, bb[0], offs_all + OOFF[0], ssrc_all + SOFF[0], rstb, 50000);
    gemm_mfma<1, 0><<<dim3(2, 391), 256, 0, stream>>>(
        xb, Wst[0], rstb, bs[0], nullptr, nullptr, nullptr, nullptr, h1b, 50000, 256, 128, 0);

    // ---- layer 1 (D=64, cin=256) ----
    gemm_mfma<0, 1><<<dim3(2, 391), 256, 0, stream>>>(
        h1b, Wt[1], nullptr, nullptr, al[1], ar[1], elb, erb, fsb, 50000, 256, 256, 10000);
    attn_agg64<<<2500, 256, 0, stream>>>(fsb, elb, erb, bb[1], offs_all + OOFF[1], ssrc_all + SOFF[1], rstb, 10000);
    gemm_mfma<1, 0><<<dim3(2, 79), 256, 0, stream>>>(
        h1b, Wst[1], rstb, bs[1], nullptr, nullptr, nullptr, nullptr, h2b, 10000, 256, 256, 0);

    // ---- layer 2 (D=47, cin=256) ----
    gemm_mfma<0, 0><<<dim3(2, 79), 256, 0, stream>>>(
        h2b, Wt[2], nullptr, nullptr, nullptr, nullptr, nullptr, nullptr, fsb, 10000, 188, 256, 0);
    el_er_kernel<<<10000, 256, 0, stream>>>(fsb, al[2], ar[2], elb, erb, 2048, 47);
    attn_agg_gen<<<512, 256, 0, stream>>>(fsb, elb, erb, bb[2], offs_all + OOFF[2], ssrc_all + SOFF[2], rstb, 47, 2048);
    final_kernel<<<2048, 64, 0, stream>>>(rstb, h2b, Ws[2], bs[2], (float*)d_out);
}